// Round 10
// baseline (33.553 us; speedup 1.0000x reference)
//
#include <hip/hip_runtime.h>
#include <hip/hip_bf16.h>

#define BATCH 16384
#define NCLS  1000
#define NPAD  1024
#define FDIM  512

// cbt per cblk: 16 slabs * 16KB ([chunk4][class256]x16B) + tail 4KB
#define CBLK_STRIDE 266240
#define TAIL_OFF    262144
// xbt per bblk: 16 slabs * 16KB ([chunk4][row256]x16B)
#define XBLK_STRIDE 262144

typedef __bf16 bf16x8 __attribute__((ext_vector_type(8)));
typedef float  f32x16 __attribute__((ext_vector_type(16)));

#define GLOBAL_AS __attribute__((address_space(1)))
#define LDS_AS    __attribute__((address_space(3)))

#define VMCNT(n) asm volatile("s_waitcnt vmcnt(" #n ")" ::: "memory")
#define LGKM0()  asm volatile("s_waitcnt lgkmcnt(0)" ::: "memory")
#define SCHED0() __builtin_amdgcn_sched_barrier(0)
#define BAR()    do { LGKM0(); __builtin_amdgcn_s_barrier(); SCHED0(); } while (0)

// ---------------------------------------------------------------------------
// prep (fused): blocks 0..255   -> centers fp32 -> cbt slab images (+tail)
//               blocks 256..1279 -> x fp32 -> xbt bf16 slab images
// Also zeroes out[0] (combine atomicAdds into it on the same stream).
// ---------------------------------------------------------------------------
__global__ __launch_bounds__(256) void prep(
    const float* __restrict__ centers, const float* __restrict__ x,
    char* __restrict__ cbt, char* __restrict__ xbt, float* __restrict__ out)
{
    const int bid = blockIdx.x, t = threadIdx.x;
    if (bid == 0 && t == 0) out[0] = 0.f;

    if (bid < 256) {
        // ---- centers: one 64-lane wave per class ----
        const int lane = t & 63;
        const int c = bid * 4 + (t >> 6);            // 0..1023
        const int cblk = c >> 8, cl = c & 255;
        char* base = cbt + (size_t)cblk * CBLK_STRIDE;

        float4 f0 = make_float4(0.f, 0.f, 0.f, 0.f);
        float4 f1 = make_float4(0.f, 0.f, 0.f, 0.f);
        if (c < NCLS) {
            f0 = *(const float4*)(centers + (size_t)c * FDIM + lane * 8);
            f1 = *(const float4*)(centers + (size_t)c * FDIM + lane * 8 + 4);
        }
        bf16x8 b;
        b[0] = (__bf16)f0.x; b[1] = (__bf16)f0.y; b[2] = (__bf16)f0.z; b[3] = (__bf16)f0.w;
        b[4] = (__bf16)f1.x; b[5] = (__bf16)f1.y; b[6] = (__bf16)f1.z; b[7] = (__bf16)f1.w;
        // lane owns k-chunk lane: slab lane>>2, chunk lane&3
        *(bf16x8*)(base + (lane >> 2) * 16384 + (lane & 3) * 4096 + cl * 16) = b;

        float ssum = f0.x*f0.x + f0.y*f0.y + f0.z*f0.z + f0.w*f0.w
                   + f1.x*f1.x + f1.y*f1.y + f1.z*f1.z + f1.w*f1.w;
        #pragma unroll
        for (int o = 32; o > 0; o >>= 1) ssum += __shfl_down(ssum, o);
        if (lane == 0) {
            const float hf = (c < NCLS) ? (-0.5f * ssum) : -1e30f;
            const __bf16 h = (__bf16)hf;
            const __bf16 l = (c < NCLS) ? (__bf16)(hf - (float)h) : (__bf16)0.f;
            bf16x8 tl;
            #pragma unroll
            for (int e = 0; e < 8; ++e) tl[e] = (__bf16)0.f;
            tl[0] = h; tl[1] = l;
            *(bf16x8*)(base + TAIL_OFF + cl * 16) = tl;
        }
    } else {
        // ---- x tiling: block handles (bblk, slab); thread t = row in bblk ----
        const int pid  = bid - 256;                  // 0..1023
        const int bblk = pid >> 4, s = pid & 15;
        const float* src = x + (size_t)(bblk * 256 + t) * FDIM + s * 32;
        float4 f[8];
        #pragma unroll
        for (int j = 0; j < 8; ++j) f[j] = *(const float4*)(src + j * 4);
        char* dst = xbt + (size_t)bblk * XBLK_STRIDE + s * 16384 + t * 16;
        #pragma unroll
        for (int c = 0; c < 4; ++c) {
            bf16x8 b;
            b[0] = (__bf16)f[c*2].x;   b[1] = (__bf16)f[c*2].y;
            b[2] = (__bf16)f[c*2].z;   b[3] = (__bf16)f[c*2].w;
            b[4] = (__bf16)f[c*2+1].x; b[5] = (__bf16)f[c*2+1].y;
            b[6] = (__bf16)f[c*2+1].z; b[7] = (__bf16)f[c*2+1].w;
            *(bf16x8*)(dst + c * 4096) = b;          // lanes -> consecutive 16B
        }
    }
}

// ---------------------------------------------------------------------------
// main: classes-as-M GEMM, acc[class][batch] = dot(c,x) - cn/2  (s = -2*acc)
//  block 256 cls x 256 batch, 8 waves (2M x 4N), wave 128x64 (4x2 frags).
//  grid = 256 -> 1/CU; XCD = bid&7 = bblk&7: per-XCD working set =
//  8 xbt images (2MB) + 4 cbt images (1MB) = 3MB < 4MB L2  -> re-reads hit L2.
//  BK=32, 16 slabs, triple-buffered, depth-2, counted VMCNT(4).
//  BOTH operands staged by pure global_load_lds DMA (no cvt/ds_write in loop).
//  LDS: A 3x16K @0 | B 3x16K @48K | tail 4K @96K  (100KB)
// ---------------------------------------------------------------------------
__global__ __launch_bounds__(512, 1) void trip_main(
    const int* __restrict__ labels, const char* __restrict__ cbt,
    const char* __restrict__ xbt, float* __restrict__ mxp,
    float* __restrict__ dap)
{
    extern __shared__ char lds[];
    const int t    = threadIdx.x;
    const int lane = t & 63;
    const int w    = t >> 6;          // 0..7
    const int wN   = w & 3, wM = w >> 2;
    const int l31  = lane & 31, hi = lane >> 5;
    const int bid  = blockIdx.x;
    const int cblk = bid >> 6;        // 0..3
    const int bblk = bid & 63;        // 0..63 -> XCD = bblk & 7
    const int class0 = cblk * 256;
    const int row0   = bblk * 256;
    const char* cbB  = cbt + (size_t)cblk * CBLK_STRIDE;
    const char* xbB  = xbt + (size_t)bblk * XBLK_STRIDE;

    auto stageA = [&](int ko, int ai) {   // 16KB contiguous DMA, 2 instr
        const char* src = cbB + ko * 16384 + t * 16;
        char* dst = lds + ai * 16384 + t * 16;
        __builtin_amdgcn_global_load_lds((const GLOBAL_AS void*)src,
                                         (LDS_AS void*)dst, 16, 0, 0);
        __builtin_amdgcn_global_load_lds((const GLOBAL_AS void*)(src + 8192),
                                         (LDS_AS void*)(dst + 8192), 16, 0, 0);
    };
    auto stageB = [&](int ko, int bi) {   // 16KB contiguous DMA, 2 instr
        const char* src = xbB + ko * 16384 + t * 16;
        char* dst = lds + 49152 + bi * 16384 + t * 16;
        __builtin_amdgcn_global_load_lds((const GLOBAL_AS void*)src,
                                         (LDS_AS void*)dst, 16, 0, 0);
        __builtin_amdgcn_global_load_lds((const GLOBAL_AS void*)(src + 8192),
                                         (LDS_AS void*)(dst + 8192), 16, 0, 0);
    };

    f32x16 acc[4][2];
    #pragma unroll
    for (int mi = 0; mi < 4; ++mi)
        #pragma unroll
        for (int ni = 0; ni < 2; ++ni)
            #pragma unroll
            for (int r = 0; r < 16; ++r) acc[mi][ni][r] = 0.f;

    auto compute = [&](int buf) {
        const char* A = lds + buf * 16384;
        const char* B = lds + 49152 + buf * 16384;
        #pragma unroll
        for (int ks = 0; ks < 2; ++ks) {
            const int chunk = ks * 2 + hi;
            bf16x8 a[4], b[2];
            #pragma unroll
            for (int mi = 0; mi < 4; ++mi)
                a[mi] = *(const bf16x8*)(A + chunk * 4096 + (wM * 128 + mi * 32 + l31) * 16);
            #pragma unroll
            for (int ni = 0; ni < 2; ++ni)
                b[ni] = *(const bf16x8*)(B + chunk * 4096 + (wN * 64 + ni * 32 + l31) * 16);
            #pragma unroll
            for (int mi = 0; mi < 4; ++mi)
                #pragma unroll
                for (int ni = 0; ni < 2; ++ni)
                    acc[mi][ni] = __builtin_amdgcn_mfma_f32_32x32x16_bf16(
                        a[mi], b[ni], acc[mi][ni], 0, 0, 0);
        }
    };

    // ---- prologue (ledger: lab 2 | tail 1(w<4) | A0 2, B0 2 | A1 2, B1 2) ----
    const int lab0 = labels[row0 + wN * 64 + l31];
    const int lab1 = labels[row0 + wN * 64 + 32 + l31];
    SCHED0();                            // labels issued first
    if (t < 256) {   // tail A: 4KB DMA (wave-uniform branch, waves 0-3)
        const char* src = cbB + TAIL_OFF + t * 16;
        char* dst = lds + 98304 + t * 16;
        __builtin_amdgcn_global_load_lds((const GLOBAL_AS void*)src,
                                         (LDS_AS void*)dst, 16, 0, 0);
    }
    stageA(0, 0); stageB(0, 0);
    SCHED0();                            // {lab,tail,slab0} before slab1
    stageA(1, 1); stageB(1, 1);
    VMCNT(4);                            // drain lab+tail+slab0; keep slab1's 4
    BAR();

    // ---- K pipeline: 16 slabs of 32, FULLY UNROLLED, triple-buffered ----
    #pragma unroll
    for (int tt = 0; tt < 16; ++tt) {
        if (tt < 14) {
            const int pre = (tt + 2) % 3;
            stageA(tt + 2, pre);
            stageB(tt + 2, pre);
            VMCNT(4);                    // drain slab tt+1; keep slab tt+2
        } else if (tt == 14) {
            VMCNT(0);                    // drain slab 15
        }
        compute(tt % 3);
        BAR();                           // slab tt+1 visible to all waves
    }

    // ---- tail k-step (k 512..527): A from tail LDS, B = (1,1,0,...) ----
    {
        const char* T = lds + 98304;
        bf16x8 bt;
        #pragma unroll
        for (int e = 0; e < 8; ++e) bt[e] = (__bf16)0.f;
        if (hi == 0) { bt[0] = (__bf16)1.0f; bt[1] = (__bf16)1.0f; }
        #pragma unroll
        for (int mi = 0; mi < 4; ++mi) {
            bf16x8 a = *(const bf16x8*)(T + (wM * 128 + mi * 32 + l31) * 16);
            #pragma unroll
            for (int ni = 0; ni < 2; ++ni)
                acc[mi][ni] = __builtin_amdgcn_mfma_f32_32x32x16_bf16(
                    a, bt, acc[mi][ni], 0, 0, 0);
        }
    }

    // ---- epilogue: per-lane max over non-label classes + label acc ----
    const int labBase = class0 + wM * 128 + hi * 4;
    const int labA0 = lab0 - labBase;
    const int labA1 = lab1 - labBase;
    float MX0 = -3e38f, MX1 = -3e38f, DA0 = -3e38f, DA1 = -3e38f;
    #pragma unroll
    for (int mi = 0; mi < 4; ++mi) {
        #pragma unroll
        for (int r = 0; r < 16; ++r) {
            const int pat = mi * 32 + (r & 3) + 8 * (r >> 2);
            {
                const float a = acc[mi][0][r];
                const bool is = (labA0 == pat);
                MX0 = fmaxf(MX0, is ? -3e38f : a);
                DA0 = is ? a : DA0;
            }
            {
                const float a = acc[mi][1][r];
                const bool is = (labA1 == pat);
                MX1 = fmaxf(MX1, is ? -3e38f : a);
                DA1 = is ? a : DA1;
            }
        }
    }
    MX0 = fmaxf(MX0, __shfl_xor(MX0, 32));
    DA0 = fmaxf(DA0, __shfl_xor(DA0, 32));
    MX1 = fmaxf(MX1, __shfl_xor(MX1, 32));
    DA1 = fmaxf(DA1, __shfl_xor(DA1, 32));

    // ---- merge the two M-waves via scratch (A buf0, retired), store ----
    float* sc = (float*)lds;              // [256] MX, [256] DA
    const int i0 = (wN * 2 + 0) * 32 + l31;
    const int i1 = (wN * 2 + 1) * 32 + l31;
    if (wM == 1 && hi == 0) {
        sc[i0] = MX0; sc[256 + i0] = DA0;
        sc[i1] = MX1; sc[256 + i1] = DA1;
    }
    __syncthreads();
    if (wM == 0 && hi == 0) {
        const float M0 = fmaxf(MX0, sc[i0]),  D0 = fmaxf(DA0, sc[256 + i0]);
        const float M1 = fmaxf(MX1, sc[i1]),  D1 = fmaxf(DA1, sc[256 + i1]);
        const int rg = row0 + wN * 64 + l31;
        mxp[cblk * BATCH + rg]      = M0;
        dap[cblk * BATCH + rg]      = D0;
        mxp[cblk * BATCH + rg + 32] = M1;
        dap[cblk * BATCH + rg + 32] = D1;
    }
}

// ---------------------------------------------------------------------------
// combine: fold 4 cblk partials, hinge, block-sum, one atomicAdd per block.
// out[0] zeroed by prep (stream-ordered before this kernel).
// ---------------------------------------------------------------------------
__global__ __launch_bounds__(256) void combine(
    const float* __restrict__ mxp, const float* __restrict__ dap,
    const float* __restrict__ margin, float* __restrict__ out)
{
    const int t = threadIdx.x;
    const int row = blockIdx.x * 256 + t;
    float mx = fmaxf(fmaxf(mxp[row], mxp[BATCH + row]),
                     fmaxf(mxp[2 * BATCH + row], mxp[3 * BATCH + row]));
    float da = fmaxf(fmaxf(dap[row], dap[BATCH + row]),
                     fmaxf(dap[2 * BATCH + row], dap[3 * BATCH + row]));
    // dist = -2*da, dist_min = -2*mx
    float loss = fmaxf(margin[0] - 2.f * da + 2.f * mx, 0.f);
    __shared__ float red[4];
    #pragma unroll
    for (int o = 32; o > 0; o >>= 1) loss += __shfl_down(loss, o);
    if ((t & 63) == 0) red[t >> 6] = loss;
    __syncthreads();
    if (t == 0)
        atomicAdd(out, (red[0] + red[1] + red[2] + red[3]) * (1.0f / BATCH));
}

// ---------------------------------------------------------------------------
extern "C" void kernel_launch(void* const* d_in, const int* in_sizes, int n_in,
                              void* d_out, int out_size, void* d_ws, size_t ws_size,
                              hipStream_t stream)
{
    const float* x       = (const float*)d_in[0];
    const int*   labels  = (const int*)d_in[1];
    const float* centers = (const float*)d_in[2];
    const float* margin  = (const float*)d_in[3];
    float* out = (float*)d_out;

    char* ws = (char*)d_ws;
    char*  cbt  = ws;                                  //  1,064,960 B
    char*  xbt  = ws + 1064960;                        // 16,777,216 B
    float* mxp  = (float*)(ws + 17842176);             //    262,144 B
    float* dap  = (float*)(ws + 18104320);             //    262,144 B

    (void)hipFuncSetAttribute((const void*)trip_main,
                              hipFuncAttributeMaxDynamicSharedMemorySize, 102400);

    prep<<<1280, 256, 0, stream>>>(centers, x, cbt, xbt, out);
    trip_main<<<256, 512, 102400, stream>>>(labels, cbt, xbt, mxp, dap);
    combine<<<64, 256, 0, stream>>>(mxp, dap, margin, out);
}

// Round 11
// 33.236 us; speedup vs baseline: 1.0095x; 1.0095x over previous
//
#include <hip/hip_runtime.h>
#include <hip/hip_bf16.h>

#define BATCH 16384
#define NCLS  1000
#define NPAD  1024
#define FDIM  512

// cbt per cblk: 8 K-tiles * 32KB ([chunk8][class256]x16B) + tail 4KB
#define CBLK_STRIDE 266240
#define TAIL_OFF    262144
// xbt per bblk: 8 K-tiles * 32KB ([chunk8][row256]x16B)
#define XBLK_STRIDE 262144

typedef __bf16 bf16x8 __attribute__((ext_vector_type(8)));
typedef float  f32x16 __attribute__((ext_vector_type(16)));

#define GLOBAL_AS __attribute__((address_space(1)))
#define LDS_AS    __attribute__((address_space(3)))

#define VMCNT(n) asm volatile("s_waitcnt vmcnt(" #n ")" ::: "memory")
#define LGKM0()  asm volatile("s_waitcnt lgkmcnt(0)" ::: "memory")
#define SBAR()   __builtin_amdgcn_s_barrier()
#define SCHED0() __builtin_amdgcn_sched_barrier(0)

// ---------------------------------------------------------------------------
// prep (fused): blocks 0..255  -> centers fp32 -> cbt K-tile images (+tail)
//               blocks 256..767 -> x fp32 -> xbt bf16 K-tile images
// Also zeroes out[0] (combine atomicAdds into it on the same stream).
// ---------------------------------------------------------------------------
__global__ __launch_bounds__(256) void prep(
    const float* __restrict__ centers, const float* __restrict__ x,
    char* __restrict__ cbt, char* __restrict__ xbt, float* __restrict__ out)
{
    const int bid = blockIdx.x, t = threadIdx.x;
    if (bid == 0 && t == 0) out[0] = 0.f;

    if (bid < 256) {
        // ---- centers: one 64-lane wave per class ----
        const int lane = t & 63;
        const int c = bid * 4 + (t >> 6);            // 0..1023
        const int cblk = c >> 8, cl = c & 255;
        char* base = cbt + (size_t)cblk * CBLK_STRIDE;

        float4 f0 = make_float4(0.f, 0.f, 0.f, 0.f);
        float4 f1 = make_float4(0.f, 0.f, 0.f, 0.f);
        if (c < NCLS) {
            f0 = *(const float4*)(centers + (size_t)c * FDIM + lane * 8);
            f1 = *(const float4*)(centers + (size_t)c * FDIM + lane * 8 + 4);
        }
        bf16x8 b;
        b[0] = (__bf16)f0.x; b[1] = (__bf16)f0.y; b[2] = (__bf16)f0.z; b[3] = (__bf16)f0.w;
        b[4] = (__bf16)f1.x; b[5] = (__bf16)f1.y; b[6] = (__bf16)f1.z; b[7] = (__bf16)f1.w;
        // lane owns k-chunk lane: K-tile lane>>3, chunk lane&7
        *(bf16x8*)(base + (lane >> 3) * 32768 + (lane & 7) * 4096 + cl * 16) = b;

        float ssum = f0.x*f0.x + f0.y*f0.y + f0.z*f0.z + f0.w*f0.w
                   + f1.x*f1.x + f1.y*f1.y + f1.z*f1.z + f1.w*f1.w;
        #pragma unroll
        for (int o = 32; o > 0; o >>= 1) ssum += __shfl_down(ssum, o);
        if (lane == 0) {
            const float hf = (c < NCLS) ? (-0.5f * ssum) : -1e30f;
            const __bf16 h = (__bf16)hf;
            const __bf16 l = (c < NCLS) ? (__bf16)(hf - (float)h) : (__bf16)0.f;
            bf16x8 tl;
            #pragma unroll
            for (int e = 0; e < 8; ++e) tl[e] = (__bf16)0.f;
            tl[0] = h; tl[1] = l;
            *(bf16x8*)(base + TAIL_OFF + cl * 16) = tl;
        }
    } else {
        // ---- x tiling: block = (bblk, K-tile); thread t = row in bblk ----
        const int pid  = bid - 256;                  // 0..511
        const int bblk = pid >> 3, s = pid & 7;
        const float* src = x + (size_t)(bblk * 256 + t) * FDIM + s * 64;
        float4 f[16];
        #pragma unroll
        for (int j = 0; j < 16; ++j) f[j] = *(const float4*)(src + j * 4);
        char* dst = xbt + (size_t)bblk * XBLK_STRIDE + s * 32768 + t * 16;
        #pragma unroll
        for (int c = 0; c < 8; ++c) {
            bf16x8 b;
            b[0] = (__bf16)f[c*2].x;   b[1] = (__bf16)f[c*2].y;
            b[2] = (__bf16)f[c*2].z;   b[3] = (__bf16)f[c*2].w;
            b[4] = (__bf16)f[c*2+1].x; b[5] = (__bf16)f[c*2+1].y;
            b[6] = (__bf16)f[c*2+1].z; b[7] = (__bf16)f[c*2+1].w;
            *(bf16x8*)(dst + c * 4096) = b;          // coalesced per chunk
        }
    }
}

// ---------------------------------------------------------------------------
// main: classes-as-M GEMM, acc[class][batch] = dot(c,x) - cn/2  (s = -2*acc)
//  *** faithful m201 8-phase template port ***
//  block 256 cls x 256 batch, 8 waves (2M x 4N), wave 128x64 (4x2 frags).
//  grid 256 -> 1/CU; XCD = bid&7 = bblk&7 (x images L2-resident per XCD).
//  K = 8 tiles of 64; tile T in buf T&1; 4 phases/tile (unit u = chunk pair).
//  Phase (T,u): VMCNT(4) [drains unit consumed at NEXT phase; this phase's
//  unit was drained+barrier'd last phase -> cross-wave visible] ->
//  6 ds_read_b128 -> stage unit u of tile T+1 (2 global_load_lds; consumed
//  4 phases later; region's last reader 4 barrier-pairs ago) ->
//  SBAR -> lgkmcnt(0) -> setprio(1) 8 MFMA setprio(0) -> SBAR.
//  LDS: A 2x32K @0 | B 2x32K @64K | tail 4K @128K  (132KB, 1 block/CU)
// ---------------------------------------------------------------------------
__global__ __launch_bounds__(512, 1) void trip_main(
    const int* __restrict__ labels, const char* __restrict__ cbt,
    const char* __restrict__ xbt, float* __restrict__ mxp,
    float* __restrict__ dap)
{
    extern __shared__ char lds[];
    const int t    = threadIdx.x;
    const int lane = t & 63;
    const int w    = t >> 6;          // 0..7
    const int wN   = w & 3, wM = w >> 2;
    const int l31  = lane & 31, hi = lane >> 5;
    const int bid  = blockIdx.x;
    const int cblk = bid >> 6;        // 0..3
    const int bblk = bid & 63;        // 0..63 -> XCD = bblk & 7
    const int class0 = cblk * 256;
    const int row0   = bblk * 256;
    const char* cbB  = cbt + (size_t)cblk * CBLK_STRIDE;
    const char* xbB  = xbt + (size_t)bblk * XBLK_STRIDE;

    auto stageU = [&](int T, int u) {     // one unit: A 8KB + B 8KB, 2 DMA
        const int boff = (T & 1) * 32768 + u * 8192 + t * 16;
        const int goff = T * 32768 + u * 8192 + t * 16;
        __builtin_amdgcn_global_load_lds((const GLOBAL_AS void*)(cbB + goff),
                                         (LDS_AS void*)(lds + boff), 16, 0, 0);
        __builtin_amdgcn_global_load_lds((const GLOBAL_AS void*)(xbB + goff),
                                         (LDS_AS void*)(lds + 65536 + boff), 16, 0, 0);
    };

    f32x16 acc[4][2];
    #pragma unroll
    for (int mi = 0; mi < 4; ++mi)
        #pragma unroll
        for (int ni = 0; ni < 2; ++ni)
            #pragma unroll
            for (int r = 0; r < 16; ++r) acc[mi][ni][r] = 0.f;

    // ---- prologue (vmem FIFO: lab 2, tail 1(w<4), t0u0..u3 2 each) ----
    const int lab0 = labels[row0 + wN * 64 + l31];
    const int lab1 = labels[row0 + wN * 64 + 32 + l31];
    SCHED0();
    if (t < 256) {   // tail A: 4KB DMA (wave-uniform branch, waves 0-3)
        const char* src = cbB + TAIL_OFF + t * 16;
        char* dst = lds + 131072 + t * 16;
        __builtin_amdgcn_global_load_lds((const GLOBAL_AS void*)src,
                                         (LDS_AS void*)dst, 16, 0, 0);
    }
    SCHED0();
    stageU(0, 0); SCHED0();
    stageU(0, 1); SCHED0();
    stageU(0, 2); SCHED0();
    stageU(0, 3);
    VMCNT(6);                 // drain lab+tail+t0u0; keep u1,u2,u3 (6 loads)
    SBAR(); SCHED0();         // t0u0 visible to all waves

    // ---- 32 phases, FULLY UNROLLED ----
    #pragma unroll
    for (int T = 0; T < 8; ++T) {
        const char* A = lds + (T & 1) * 32768;
        const char* B = lds + 65536 + (T & 1) * 32768;
        #pragma unroll
        for (int u = 0; u < 4; ++u) {
            // counted vm-wait: drain the unit consumed NEXT phase
            if (T < 7)          VMCNT(4);
            else if (u == 0)    VMCNT(4);
            else if (u == 1)    VMCNT(2);
            else if (u == 2)    VMCNT(0);
            // ds_read fragments for THIS phase (unit u, visible since last
            // phase's vmcnt+barrier)
            const int chunk = u * 2 + hi;
            bf16x8 a0 = *(const bf16x8*)(A + chunk * 4096 + (wM * 128 +  0 + l31) * 16);
            bf16x8 a1 = *(const bf16x8*)(A + chunk * 4096 + (wM * 128 + 32 + l31) * 16);
            bf16x8 a2 = *(const bf16x8*)(A + chunk * 4096 + (wM * 128 + 64 + l31) * 16);
            bf16x8 a3 = *(const bf16x8*)(A + chunk * 4096 + (wM * 128 + 96 + l31) * 16);
            bf16x8 b0 = *(const bf16x8*)(B + chunk * 4096 + (wN * 64 +  0 + l31) * 16);
            bf16x8 b1 = *(const bf16x8*)(B + chunk * 4096 + (wN * 64 + 32 + l31) * 16);
            // stage unit u of tile T+1 (into the buffer NOT being read)
            if (T < 7) stageU(T + 1, u);
            SBAR();
            LGKM0();
            SCHED0();
            __builtin_amdgcn_s_setprio(1);
            acc[0][0] = __builtin_amdgcn_mfma_f32_32x32x16_bf16(a0, b0, acc[0][0], 0, 0, 0);
            acc[0][1] = __builtin_amdgcn_mfma_f32_32x32x16_bf16(a0, b1, acc[0][1], 0, 0, 0);
            acc[1][0] = __builtin_amdgcn_mfma_f32_32x32x16_bf16(a1, b0, acc[1][0], 0, 0, 0);
            acc[1][1] = __builtin_amdgcn_mfma_f32_32x32x16_bf16(a1, b1, acc[1][1], 0, 0, 0);
            acc[2][0] = __builtin_amdgcn_mfma_f32_32x32x16_bf16(a2, b0, acc[2][0], 0, 0, 0);
            acc[2][1] = __builtin_amdgcn_mfma_f32_32x32x16_bf16(a2, b1, acc[2][1], 0, 0, 0);
            acc[3][0] = __builtin_amdgcn_mfma_f32_32x32x16_bf16(a3, b0, acc[3][0], 0, 0, 0);
            acc[3][1] = __builtin_amdgcn_mfma_f32_32x32x16_bf16(a3, b1, acc[3][1], 0, 0, 0);
            __builtin_amdgcn_s_setprio(0);
            SBAR();
            SCHED0();
        }
    }

    // ---- tail k-step (k 512..527): A from tail LDS, B = (1,1,0,...) ----
    {
        const char* T = lds + 131072;
        bf16x8 bt;
        #pragma unroll
        for (int e = 0; e < 8; ++e) bt[e] = (__bf16)0.f;
        if (hi == 0) { bt[0] = (__bf16)1.0f; bt[1] = (__bf16)1.0f; }
        #pragma unroll
        for (int mi = 0; mi < 4; ++mi) {
            bf16x8 a = *(const bf16x8*)(T + (wM * 128 + mi * 32 + l31) * 16);
            #pragma unroll
            for (int ni = 0; ni < 2; ++ni)
                acc[mi][ni] = __builtin_amdgcn_mfma_f32_32x32x16_bf16(
                    a, bt, acc[mi][ni], 0, 0, 0);
        }
    }

    // ---- epilogue: per-lane max over non-label classes + label acc ----
    const int labBase = class0 + wM * 128 + hi * 4;
    const int labA0 = lab0 - labBase;
    const int labA1 = lab1 - labBase;
    float MX0 = -3e38f, MX1 = -3e38f, DA0 = -3e38f, DA1 = -3e38f;
    #pragma unroll
    for (int mi = 0; mi < 4; ++mi) {
        #pragma unroll
        for (int r = 0; r < 16; ++r) {
            const int pat = mi * 32 + (r & 3) + 8 * (r >> 2);
            {
                const float a = acc[mi][0][r];
                const bool is = (labA0 == pat);
                MX0 = fmaxf(MX0, is ? -3e38f : a);
                DA0 = is ? a : DA0;
            }
            {
                const float a = acc[mi][1][r];
                const bool is = (labA1 == pat);
                MX1 = fmaxf(MX1, is ? -3e38f : a);
                DA1 = is ? a : DA1;
            }
        }
    }
    MX0 = fmaxf(MX0, __shfl_xor(MX0, 32));
    DA0 = fmaxf(DA0, __shfl_xor(DA0, 32));
    MX1 = fmaxf(MX1, __shfl_xor(MX1, 32));
    DA1 = fmaxf(DA1, __shfl_xor(DA1, 32));

    // ---- merge the two M-waves via scratch (A buf0, retired), store ----
    float* sc = (float*)lds;              // [256] MX, [256] DA
    const int i0 = (wN * 2 + 0) * 32 + l31;
    const int i1 = (wN * 2 + 1) * 32 + l31;
    __syncthreads();
    if (wM == 1 && hi == 0) {
        sc[i0] = MX0; sc[256 + i0] = DA0;
        sc[i1] = MX1; sc[256 + i1] = DA1;
    }
    __syncthreads();
    if (wM == 0 && hi == 0) {
        const float M0 = fmaxf(MX0, sc[i0]),  D0 = fmaxf(DA0, sc[256 + i0]);
        const float M1 = fmaxf(MX1, sc[i1]),  D1 = fmaxf(DA1, sc[256 + i1]);
        const int rg = row0 + wN * 64 + l31;
        mxp[cblk * BATCH + rg]      = M0;
        dap[cblk * BATCH + rg]      = D0;
        mxp[cblk * BATCH + rg + 32] = M1;
        dap[cblk * BATCH + rg + 32] = D1;
    }
}

// ---------------------------------------------------------------------------
// combine: fold 4 cblk partials, hinge, block-sum, one atomicAdd per block.
// out[0] zeroed by prep (stream-ordered before this kernel).
// ---------------------------------------------------------------------------
__global__ __launch_bounds__(256) void combine(
    const float* __restrict__ mxp, const float* __restrict__ dap,
    const float* __restrict__ margin, float* __restrict__ out)
{
    const int t = threadIdx.x;
    const int row = blockIdx.x * 256 + t;
    float mx = fmaxf(fmaxf(mxp[row], mxp[BATCH + row]),
                     fmaxf(mxp[2 * BATCH + row], mxp[3 * BATCH + row]));
    float da = fmaxf(fmaxf(dap[row], dap[BATCH + row]),
                     fmaxf(dap[2 * BATCH + row], dap[3 * BATCH + row]));
    // dist = -2*da, dist_min = -2*mx
    float loss = fmaxf(margin[0] - 2.f * da + 2.f * mx, 0.f);
    __shared__ float red[4];
    #pragma unroll
    for (int o = 32; o > 0; o >>= 1) loss += __shfl_down(loss, o);
    if ((t & 63) == 0) red[t >> 6] = loss;
    __syncthreads();
    if (t == 0)
        atomicAdd(out, (red[0] + red[1] + red[2] + red[3]) * (1.0f / BATCH));
}

// ---------------------------------------------------------------------------
extern "C" void kernel_launch(void* const* d_in, const int* in_sizes, int n_in,
                              void* d_out, int out_size, void* d_ws, size_t ws_size,
                              hipStream_t stream)
{
    const float* x       = (const float*)d_in[0];
    const int*   labels  = (const int*)d_in[1];
    const float* centers = (const float*)d_in[2];
    const float* margin  = (const float*)d_in[3];
    float* out = (float*)d_out;

    char* ws = (char*)d_ws;
    char*  cbt  = ws;                                  //  1,064,960 B
    char*  xbt  = ws + 1064960;                        // 16,777,216 B
    float* mxp  = (float*)(ws + 17842176);             //    262,144 B
    float* dap  = (float*)(ws + 18104320);             //    262,144 B

    (void)hipFuncSetAttribute((const void*)trip_main,
                              hipFuncAttributeMaxDynamicSharedMemorySize, 135168);

    prep<<<768, 256, 0, stream>>>(centers, x, cbt, xbt, out);
    trip_main<<<256, 512, 135168, stream>>>(labels, cbt, xbt, mxp, dap);
    combine<<<64, 256, 0, stream>>>(mxp, dap, margin, out);
}